// Round 2
// baseline (617.501 us; speedup 1.0000x reference)
//
#include <hip/hip_runtime.h>

// RelativePosition: out[b,i,j,:] = (W[clip(ri[b,j]-ri[b,i],-32,32)+33] + bias) * (m[b,i]*m[b,j])
// B=2, L=768, C_Z=128, NUM_CLASSES=66. Output 2*768*768*128 f32 = 604 MB -> store-BW bound.

constexpr int BINS = 32;
constexpr int CZ   = 128;
constexpr int NC   = 2 * BINS + 2;   // 66
constexpr int B_   = 2;
constexpr int L_   = 768;
constexpr int NPAIRS = B_ * L_ * L_; // 1,179,648
constexpr int GROUPS_PER_BLOCK = 8;  // 256 threads / 32 lanes-per-pair
constexpr int NBLOCKS = 2048;        // grid-stride; amortizes 33 KB LDS staging

typedef float vfloat4 __attribute__((ext_vector_type(4)));  // native clang vector (nontemporal-store compatible)

__global__ __launch_bounds__(256) void relpos_kernel(
    const int*  __restrict__ residue_index,   // [B,L] int32
    const void* __restrict__ residue_mask,    // [B,L] bool (byte or int32 layout, detected)
    const float* __restrict__ W,              // [NC, CZ]
    const float* __restrict__ bias,           // [CZ]
    float* __restrict__ out)                  // [B,L,L,CZ]
{
    __shared__ float wb[NC * CZ];     // 33 KB: W + bias, precomputed
    __shared__ int   ridx[B_ * L_];   // 6 KB
    __shared__ float maskf[B_ * L_];  // 6 KB: mask as 0/1 float

    const int tid = threadIdx.x;

    // Detect mask layout (wave-uniform, cached read).
    // All-true mask: bytes -> 0x01010101 (high bytes nonzero); int32 -> 0x00000001.
    const unsigned int v0 = *(const unsigned int*)residue_mask;
    const bool byte_layout = (v0 & 0xFFFFFF00u) != 0u;

    // Stage Wb = W + bias into LDS (vectorized; NC*CZ/4 = 2112 float4s).
    const vfloat4* W4  = (const vfloat4*)W;
    const vfloat4* bi4 = (const vfloat4*)bias;
    vfloat4* wb4 = (vfloat4*)wb;
    for (int k = tid; k < NC * CZ / 4; k += 256) {
        vfloat4 w = W4[k];
        w += bi4[k & (CZ / 4 - 1)];
        wb4[k] = w;
    }
    // Stage residue_index and mask.
    for (int k = tid; k < B_ * L_; k += 256) {
        ridx[k] = residue_index[k];
        int m = byte_layout ? (int)((const unsigned char*)residue_mask)[k]
                            : ((const int*)residue_mask)[k];
        maskf[k] = m ? 1.0f : 0.0f;
    }
    __syncthreads();

    const int group = tid >> 5;   // 0..7: one 32-lane group per pair
    const int lane  = tid & 31;   // lane*4 .. lane*4+3 channels -> float4

    int p = blockIdx.x * GROUPS_PER_BLOCK + group;
    const int pstride = gridDim.x * GROUPS_PER_BLOCK;
    for (; p < NPAIRS; p += pstride) {
        const int b = p / (L_ * L_);
        const int r = p - b * (L_ * L_);
        const int i = r / L_;
        const int j = r - i * L_;
        const int o = b * L_;

        const int diff = ridx[o + j] - ridx[o + i];   // ref: ri[:,None,:] - ri[:,:,None]
        const int idx  = min(max(diff, -BINS), BINS) + BINS + 1;  // [1, 65]
        const float m  = maskf[o + i] * maskf[o + j];

        vfloat4 v = ((const vfloat4*)(wb + idx * CZ))[lane];
        v *= m;

        // 32 lanes x 16 B = 512 B contiguous per pair; write-once -> nontemporal.
        __builtin_nontemporal_store(v, (vfloat4*)(out + (size_t)p * CZ) + lane);
    }
}

extern "C" void kernel_launch(void* const* d_in, const int* in_sizes, int n_in,
                              void* d_out, int out_size, void* d_ws, size_t ws_size,
                              hipStream_t stream) {
    const int*  residue_index = (const int*)d_in[0];
    const void* residue_mask  = d_in[1];
    const float* W    = (const float*)d_in[2];
    const float* bias = (const float*)d_in[3];
    float* out = (float*)d_out;

    relpos_kernel<<<NBLOCKS, 256, 0, stream>>>(residue_index, residue_mask, W, bias, out);
}

// Round 3
// 599.884 us; speedup vs baseline: 1.0294x; 1.0294x over previous
//
#include <hip/hip_runtime.h>

// RelativePosition: out[b,i,j,:] = (W[clip(ri[b,j]-ri[b,i],-32,32)+33] + bias) * (m[b,i]*m[b,j])
// B=2, L=768, C_Z=128, NUM_CLASSES=66. Output 2*768*768*128 f32 = 604 MB -> store-BW bound.
//
// R2 -> R3: NT stores replaced with plain stores (harness memset proves plain
// stores hit 6.3 TB/s; NT was suspected sub-line write-through). Row-per-block
// layout kills per-iteration int div; unroll 4 gives independent store chains.

constexpr int BINS = 32;
constexpr int CZ   = 128;
constexpr int NC   = 2 * BINS + 2;   // 66
constexpr int B_   = 2;
constexpr int L_   = 768;
constexpr int NROWS = B_ * L_;       // 1536 blocks: one per output row [b,i]

typedef float vfloat4 __attribute__((ext_vector_type(4)));

__global__ __launch_bounds__(256) void relpos_row_kernel(
    const int*  __restrict__ residue_index,   // [B,L] int32
    const void* __restrict__ residue_mask,    // [B,L] bool (byte or int32 layout, detected)
    const float* __restrict__ W,              // [NC, CZ]
    const float* __restrict__ bias,           // [CZ]
    float* __restrict__ out)                  // [B,L,L,CZ]
{
    __shared__ float wb[NC * CZ];     // 33 KB: W + bias
    __shared__ int   ridx_row[L_];    // 3 KB: this batch's residue_index row
    __shared__ float mask_row[L_];    // 3 KB: this batch's mask row as 0/1 float

    const int tid = threadIdx.x;
    const int row = blockIdx.x;       // b*L + i
    const int b   = row / L_;         // once per block (compiler magic-mul)
    const int i   = row - b * L_;
    const int o   = b * L_;

    // Detect mask layout (wave-uniform, L2-cached).
    const unsigned int v0 = *(const unsigned int*)residue_mask;
    const bool byte_layout = (v0 & 0xFFFFFF00u) != 0u;

    // Stage Wb = W + bias (2112 float4s).
    const vfloat4* W4  = (const vfloat4*)W;
    const vfloat4* bi4 = (const vfloat4*)bias;
    vfloat4* wb4 = (vfloat4*)wb;
    for (int k = tid; k < NC * CZ / 4; k += 256) {
        wb4[k] = W4[k] + bi4[k & (CZ / 4 - 1)];
    }
    // Stage this batch's index/mask row.
    for (int k = tid; k < L_; k += 256) {
        ridx_row[k] = residue_index[o + k];
        int m = byte_layout ? (int)((const unsigned char*)residue_mask)[o + k]
                            : ((const int*)residue_mask)[o + k];
        mask_row[k] = m ? 1.0f : 0.0f;
    }
    __syncthreads();

    const int   ri_i = ridx_row[i];   // hoisted: fixed for the whole row
    const float m_i  = mask_row[i];

    const int group = tid >> 5;       // 0..7: one 32-lane group per pair (b,i,j)
    const int lane  = tid & 31;       // lane handles channels 4*lane..4*lane+3
    float* rowout = out + (size_t)row * L_ * CZ;   // contiguous 384 KB row

    #pragma unroll 4
    for (int j = group; j < L_; j += 8) {
        const int diff = ridx_row[j] - ri_i;                      // ri[:,None,:] - ri[:,:,None]
        const int idx  = min(max(diff, -BINS), BINS) + BINS + 1;  // [1, 65]
        const float m  = m_i * mask_row[j];

        vfloat4 v = ((const vfloat4*)(wb + idx * CZ))[lane];
        v *= m;
        ((vfloat4*)(rowout + j * CZ))[lane] = v;   // plain store: L2 write-back path
    }
}

extern "C" void kernel_launch(void* const* d_in, const int* in_sizes, int n_in,
                              void* d_out, int out_size, void* d_ws, size_t ws_size,
                              hipStream_t stream) {
    const int*  residue_index = (const int*)d_in[0];
    const void* residue_mask  = d_in[1];
    const float* W    = (const float*)d_in[2];
    const float* bias = (const float*)d_in[3];
    float* out = (float*)d_out;

    relpos_row_kernel<<<NROWS, 256, 0, stream>>>(residue_index, residue_mask, W, bias, out);
}